// Round 1
// baseline (435.934 us; speedup 1.0000x reference)
//
#include <hip/hip_runtime.h>
#include <cstdint>
#include <cstddef>

typedef _Float16 f16;
typedef _Float16 f16x8 __attribute__((ext_vector_type(8)));
typedef _Float16 f16x4 __attribute__((ext_vector_type(4)));
typedef float    f32x4 __attribute__((ext_vector_type(4)));

#define MFMA16(a,b,c) __builtin_amdgcn_mfma_f32_16x16x32_f16(a, b, c, 0, 0, 0)

static __device__ __forceinline__ void gload_lds16(const void* g, void* l) {
  __builtin_amdgcn_global_load_lds(
      (const __attribute__((address_space(1))) unsigned int*)g,
      (__attribute__((address_space(3))) unsigned int*)l, 16, 0, 0);
}

// ---------------------------------------------------------------------------
// elementwise f32 -> f16 cast (vectorized)
__global__ __launch_bounds__(256) void cast_kernel(const float* __restrict__ x,
                                                   f16* __restrict__ y, int n4) {
  int i = blockIdx.x * 256 + threadIdx.x;
  if (i < n4) {
    float4 v = ((const float4*)x)[i];
    f16x4 h;
    h[0] = (f16)v.x; h[1] = (f16)v.y; h[2] = (f16)v.z; h[3] = (f16)v.w;
    *(f16x4*)(y + (size_t)i * 4) = h;
  }
}

// ---------------------------------------------------------------------------
// W [K][N] f32 row-major  ->  Wt [N][K] f16 row-major
__global__ __launch_bounds__(256) void wtrans(const float* __restrict__ W,
                                              f16* __restrict__ Wt, int K, int N) {
  __shared__ float tile[32][33];
  const int n0 = blockIdx.x * 32, k0 = blockIdx.y * 32;
  const int c = threadIdx.x & 31, r = threadIdx.x >> 5;  // r: 0..7
#pragma unroll
  for (int i = 0; i < 4; i++) {
    int row = r + i * 8;
    tile[row][c] = W[(size_t)(k0 + row) * N + n0 + c];
  }
  __syncthreads();
#pragma unroll
  for (int i = 0; i < 4; i++) {
    int row = r + i * 8;
    Wt[(size_t)(n0 + row) * K + k0 + c] = (f16)tile[c][row];
  }
}

// ---------------------------------------------------------------------------
// GEMM: out[M][N] = epilogue(A[M][K]_f16 @ W^T[N][K]_f16 + bias)
// MODE 0: f16 store   MODE 1: relu + f16 store   MODE 2: f32 store + residual
// 128x128 tile, 4 waves (2x2), BK=64, global_load_lds w/ chunk-XOR swizzle.
template <int MODE>
__global__ __launch_bounds__(256, 2)
void gemm_kernel(const f16* __restrict__ A, const f16* __restrict__ W,
                 const float* __restrict__ bias, const float* __restrict__ res,
                 void* __restrict__ out, int N, int K) {
  __shared__ __align__(16) f16 lsA[128 * 64];
  __shared__ __align__(16) f16 lsB[128 * 64];
  const int tid  = threadIdx.x;
  const int lane = tid & 63;
  const int wid  = tid >> 6;
  const int frow = lane & 15;
  const int kgrp = lane >> 4;
  const int wm = wid >> 1, wn = wid & 1;
  const int bn = blockIdx.x, bm = blockIdx.y;

  const f32x4 zero4 = {0.f, 0.f, 0.f, 0.f};
  f32x4 acc[4][4];
#pragma unroll
  for (int i = 0; i < 4; i++)
#pragma unroll
    for (int j = 0; j < 4; j++) acc[i][j] = zero4;

  const f16* aSrc[4]; const f16* bSrc[4]; int lOff[4];
#pragma unroll
  for (int i = 0; i < 4; i++) {
    int c_lin = i * 256 + wid * 64 + lane;       // chunk id (16B units)
    int row = c_lin >> 3;
    int ch  = (c_lin & 7) ^ (row & 7);           // inverse-swizzled source chunk
    aSrc[i] = A + (size_t)(bm * 128 + row) * K + ch * 8;
    bSrc[i] = W + (size_t)(bn * 128 + row) * K + ch * 8;
    lOff[i] = (i * 256 + wid * 64) * 8;          // wave-uniform LDS base (elems)
  }

  const int nk = K >> 6;
  for (int ks = 0; ks < nk; ++ks) {
#pragma unroll
    for (int i = 0; i < 4; i++) {
      gload_lds16(aSrc[i] + ks * 64, &lsA[lOff[i]]);
      gload_lds16(bSrc[i] + ks * 64, &lsB[lOff[i]]);
    }
    __syncthreads();
#pragma unroll
    for (int kk = 0; kk < 2; kk++) {
      f16x8 af[4], bf[4];
#pragma unroll
      for (int i = 0; i < 4; i++) {
        int row = wm * 64 + i * 16 + frow;
        af[i] = *(const f16x8*)&lsA[row * 64 + (((kk * 4 + kgrp) ^ (row & 7)) << 3)];
      }
#pragma unroll
      for (int j = 0; j < 4; j++) {
        int row = wn * 64 + j * 16 + frow;
        bf[j] = *(const f16x8*)&lsB[row * 64 + (((kk * 4 + kgrp) ^ (row & 7)) << 3)];
      }
#pragma unroll
      for (int i = 0; i < 4; i++)
#pragma unroll
        for (int j = 0; j < 4; j++) acc[i][j] = MFMA16(af[i], bf[j], acc[i][j]);
    }
    __syncthreads();
  }

#pragma unroll
  for (int j = 0; j < 4; j++) {
    const int col = bn * 128 + wn * 64 + j * 16 + frow;
    const float bb = bias[col];
#pragma unroll
    for (int i = 0; i < 4; i++) {
      const int row0 = bm * 128 + wm * 64 + i * 16 + kgrp * 4;
#pragma unroll
      for (int r = 0; r < 4; r++) {
        float v = acc[i][j][r] + bb;
        const size_t idx = (size_t)(row0 + r) * N + col;
        if (MODE == 1) v = fmaxf(v, 0.f);
        if (MODE == 2) ((float*)out)[idx] = v + res[idx];
        else           ((f16*)out)[idx]   = (f16)v;
      }
    }
  }
}

// ---------------------------------------------------------------------------
// Flash attention. Q/K/V: [B*S][ldq] f16, head h = cols h*64..h*64+63.
// Block: 4 waves x 16 q-rows = 64 q rows; KV tiles of 64.
__global__ __launch_bounds__(256, 2)
void attn_kernel(const f16* __restrict__ Qp, const f16* __restrict__ Kp,
                 const f16* __restrict__ Vp, f16* __restrict__ Op, int ldq) {
  __shared__ __align__(16) f16 lsK[64 * 64];
  __shared__ __align__(16) f16 lsVt[64 * 72];
  __shared__ __align__(16) f16 lsP[64 * 72];
  const int tid = threadIdx.x, lane = tid & 63, wid = tid >> 6;
  const int frow = lane & 15, kgrp = lane >> 4;
  const int qt = blockIdx.x;
  const int b = blockIdx.y >> 4, h = blockIdx.y & 15;
  const size_t rb = (size_t)b * 2048;
  const int hc = h * 64;

  f16x8 qf[2];
  {
    const f16* qp = Qp + (rb + qt * 64 + wid * 16 + frow) * ldq + hc + kgrp * 8;
    qf[0] = *(const f16x8*)qp;
    qf[1] = *(const f16x8*)(qp + 32);
  }
  const f32x4 zero4 = {0.f, 0.f, 0.f, 0.f};
  f32x4 o[4];
  float m[4], l[4];
#pragma unroll
  for (int i = 0; i < 4; i++) { o[i] = zero4; m[i] = -1e30f; l[i] = 0.f; }

  const f16* kSrc[2]; int kOff[2];
#pragma unroll
  for (int i = 0; i < 2; i++) {
    int c_lin = i * 256 + wid * 64 + lane;
    int row = c_lin >> 3, ch = (c_lin & 7) ^ (row & 7);
    kSrc[i] = Kp + (rb + row) * ldq + hc + ch * 8;
    kOff[i] = (i * 256 + wid * 64) * 8;
  }
  const f16* vSrc = Vp + (rb + lane) * ldq + hc + wid * 16;

  for (int kt = 0; kt < 32; ++kt) {
#pragma unroll
    for (int i = 0; i < 2; i++)
      gload_lds16(kSrc[i] + (size_t)kt * 64 * ldq, &lsK[kOff[i]]);
    {
      const f16* vp = vSrc + (size_t)kt * 64 * ldq;
      f16x8 v0 = *(const f16x8*)vp;
      f16x8 v1 = *(const f16x8*)(vp + 8);
#pragma unroll
      for (int jj = 0; jj < 8; jj++) lsVt[(wid * 16 + jj) * 72 + lane] = v0[jj];
#pragma unroll
      for (int jj = 0; jj < 8; jj++) lsVt[(wid * 16 + 8 + jj) * 72 + lane] = v1[jj];
    }
    __syncthreads();

    f32x4 sc[4];
#pragma unroll
    for (int nj = 0; nj < 4; nj++) sc[nj] = zero4;
#pragma unroll
    for (int kk = 0; kk < 2; kk++) {
#pragma unroll
      for (int nj = 0; nj < 4; nj++) {
        int row = nj * 16 + frow;
        f16x8 bf = *(const f16x8*)&lsK[row * 64 + (((kk * 4 + kgrp) ^ (row & 7)) << 3)];
        sc[nj] = MFMA16(qf[kk], bf, sc[nj]);
      }
    }
#pragma unroll
    for (int nj = 0; nj < 4; nj++) sc[nj] *= 0.125f;   // 1/sqrt(64)

    float fac[4];
#pragma unroll
    for (int r = 0; r < 4; r++) {
      float t = fmaxf(fmaxf(sc[0][r], sc[1][r]), fmaxf(sc[2][r], sc[3][r]));
      t = fmaxf(t, __shfl_xor(t, 1));
      t = fmaxf(t, __shfl_xor(t, 2));
      t = fmaxf(t, __shfl_xor(t, 4));
      t = fmaxf(t, __shfl_xor(t, 8));
      float mn = fmaxf(m[r], t);
      fac[r] = __expf(m[r] - mn);
      m[r] = mn;
    }
#pragma unroll
    for (int nj = 0; nj < 4; nj++)
#pragma unroll
      for (int r = 0; r < 4; r++) sc[nj][r] = __expf(sc[nj][r] - m[r]);
#pragma unroll
    for (int r = 0; r < 4; r++) {
      float ps = sc[0][r] + sc[1][r] + sc[2][r] + sc[3][r];
      ps += __shfl_xor(ps, 1);
      ps += __shfl_xor(ps, 2);
      ps += __shfl_xor(ps, 4);
      ps += __shfl_xor(ps, 8);
      l[r] = l[r] * fac[r] + ps;
#pragma unroll
      for (int dj = 0; dj < 4; dj++) o[dj][r] *= fac[r];
    }
#pragma unroll
    for (int nj = 0; nj < 4; nj++)
#pragma unroll
      for (int r = 0; r < 4; r++)
        lsP[(wid * 16 + kgrp * 4 + r) * 72 + nj * 16 + frow] = (f16)sc[nj][r];
    __syncthreads();

#pragma unroll
    for (int slab = 0; slab < 2; slab++) {
      f16x8 pa = *(const f16x8*)&lsP[(wid * 16 + frow) * 72 + slab * 32 + kgrp * 8];
#pragma unroll
      for (int dj = 0; dj < 4; dj++) {
        f16x8 vb = *(const f16x8*)&lsVt[(dj * 16 + frow) * 72 + slab * 32 + kgrp * 8];
        o[dj] = MFMA16(pa, vb, o[dj]);
      }
    }
    __syncthreads();
  }

#pragma unroll
  for (int dj = 0; dj < 4; dj++)
#pragma unroll
    for (int r = 0; r < 4; r++) {
      size_t row = rb + qt * 64 + wid * 16 + kgrp * 4 + r;
      Op[row * 1024 + hc + dj * 16 + frow] = (f16)(o[dj][r] / l[r]);
    }
}

// ---------------------------------------------------------------------------
// LayerNorm over D=1024 per row; writes f32 (of) and optional f16 (ob).
__global__ __launch_bounds__(256)
void ln_kernel(const float* __restrict__ x, const float* __restrict__ g,
               const float* __restrict__ be, float* __restrict__ of,
               f16* __restrict__ ob) {
  const int row = blockIdx.x, t = threadIdx.x;
  const float4 v = ((const float4*)(x + (size_t)row * 1024))[t];
  float s = v.x + v.y + v.z + v.w;
  float q = v.x * v.x + v.y * v.y + v.z * v.z + v.w * v.w;
#pragma unroll
  for (int off = 1; off < 64; off <<= 1) {
    s += __shfl_xor(s, off);
    q += __shfl_xor(q, off);
  }
  __shared__ float ss[4], sq[4];
  if ((t & 63) == 0) { ss[t >> 6] = s; sq[t >> 6] = q; }
  __syncthreads();
  s = ss[0] + ss[1] + ss[2] + ss[3];
  q = sq[0] + sq[1] + sq[2] + sq[3];
  const float mean = s * (1.f / 1024.f);
  const float var  = q * (1.f / 1024.f) - mean * mean;
  const float rstd = rsqrtf(var + 1e-5f);
  const float4 gv = ((const float4*)g)[t];
  const float4 bv = ((const float4*)be)[t];
  float4 ov;
  ov.x = (v.x - mean) * rstd * gv.x + bv.x;
  ov.y = (v.y - mean) * rstd * gv.y + bv.y;
  ov.z = (v.z - mean) * rstd * gv.z + bv.z;
  ov.w = (v.w - mean) * rstd * gv.w + bv.w;
  if (of) ((float4*)(of + (size_t)row * 1024))[t] = ov;
  if (ob) {
    f16x4 hv;
    hv[0] = (f16)ov.x; hv[1] = (f16)ov.y; hv[2] = (f16)ov.z; hv[3] = (f16)ov.w;
    *(f16x4*)(ob + (size_t)row * 1024 + t * 4) = hv;
  }
}

// ---------------------------------------------------------------------------
extern "C" void kernel_launch(void* const* d_in, const int* in_sizes, int n_in,
                              void* d_out, int out_size, void* d_ws, size_t ws_size,
                              hipStream_t stream) {
  const float* x   = (const float*)d_in[0];
  const float* pW1 = (const float*)d_in[1];
  const float* pb1 = (const float*)d_in[2];
  const float* pW2 = (const float*)d_in[3];
  const float* pb2 = (const float*)d_in[4];
  const float* gp  = (const float*)d_in[5];
  const float* bp  = (const float*)d_in[6];
  const float* Wq  = (const float*)d_in[7];
  const float* Wk  = (const float*)d_in[9];
  const float* Wv  = (const float*)d_in[11];
  const float* Wo  = (const float*)d_in[13];
  const float* bo  = (const float*)d_in[14];
  const float* g1  = (const float*)d_in[15];
  const float* b1  = (const float*)d_in[16];
  const float* Wf1 = (const float*)d_in[17];
  const float* bf1 = (const float*)d_in[18];
  const float* Wf2 = (const float*)d_in[19];
  const float* bf2 = (const float*)d_in[20];
  const float* g2  = (const float*)d_in[21];
  const float* b2  = (const float*)d_in[22];

  char* ws = (char*)d_ws;
  const size_t MB = 1024 * 1024;
  if (ws_size < 121 * MB) return;  // need ~120.1 MB scratch

  f16*   wtP1 = (f16*)(ws);             // [2048][1024]  4 MB
  f16*   wtP2 = (f16*)(ws + 4 * MB);    // [1024][2048]  4 MB
  f16*   wtQ  = (f16*)(ws + 8 * MB);    // [1024][1024]  2 MB (Q,K,V contiguous -> fused [3072][1024])
  f16*   wtK  = (f16*)(ws + 10 * MB);
  f16*   wtV  = (f16*)(ws + 12 * MB);
  f16*   wtO  = (f16*)(ws + 14 * MB);
  f16*   wtF1 = (f16*)(ws + 16 * MB);   // [4096][1024]  8 MB
  f16*   wtF2 = (f16*)(ws + 24 * MB);   // [1024][4096]  8 MB
  f16*   big  = (f16*)(ws + 32 * MB);   // 32 MB: h1 / fused qkv / f1
  float* t32  = (float*)(ws + 64 * MB); // 16 MB pre-LN tensor (first 8 MB also = xb)
  float* s32  = (float*)(ws + 80 * MB); // 16 MB
  float* y32  = (float*)(ws + 96 * MB); // 16 MB (first 8 MB also = sb)
  f16*   ybuf = (f16*)(ws + 112 * MB);  // 8 MB (also = ctx)
  float* bqkv = (float*)(ws + 120 * MB);// 12 KB fused qkv bias
  f16* xb  = (f16*)t32;
  f16* sb  = (f16*)y32;
  f16* ctx = ybuf;

  hipMemcpyAsync(bqkv,        d_in[8],  1024 * sizeof(float), hipMemcpyDeviceToDevice, stream);
  hipMemcpyAsync(bqkv + 1024, d_in[10], 1024 * sizeof(float), hipMemcpyDeviceToDevice, stream);
  hipMemcpyAsync(bqkv + 2048, d_in[12], 1024 * sizeof(float), hipMemcpyDeviceToDevice, stream);

  dim3 blk(256);
  cast_kernel<<<4096, blk, 0, stream>>>(x, xb, 1048576);
  wtrans<<<dim3(64, 32),  blk, 0, stream>>>(pW1, wtP1, 1024, 2048);
  wtrans<<<dim3(32, 64),  blk, 0, stream>>>(pW2, wtP2, 2048, 1024);
  wtrans<<<dim3(32, 32),  blk, 0, stream>>>(Wq,  wtQ,  1024, 1024);
  wtrans<<<dim3(32, 32),  blk, 0, stream>>>(Wk,  wtK,  1024, 1024);
  wtrans<<<dim3(32, 32),  blk, 0, stream>>>(Wv,  wtV,  1024, 1024);
  wtrans<<<dim3(32, 32),  blk, 0, stream>>>(Wo,  wtO,  1024, 1024);
  wtrans<<<dim3(128, 32), blk, 0, stream>>>(Wf1, wtF1, 1024, 4096);
  wtrans<<<dim3(32, 128), blk, 0, stream>>>(Wf2, wtF2, 4096, 1024);

  // h1 = relu(x @ pW1 + pb1)            [4096][2048] f16 in big
  gemm_kernel<1><<<dim3(16, 32), blk, 0, stream>>>(xb, wtP1, pb1, nullptr, big, 2048, 1024);
  // t = x + h1 @ pW2 + pb2              [4096][1024] f32
  gemm_kernel<2><<<dim3(8, 32), blk, 0, stream>>>(big, wtP2, pb2, x, t32, 1024, 2048);
  // s = LN(t)
  ln_kernel<<<4096, blk, 0, stream>>>(t32, gp, bp, s32, sb);
  // fused qkv = s @ [Wq|Wk|Wv] + [bq|bk|bv]   [4096][3072] f16 in big
  gemm_kernel<0><<<dim3(24, 32), blk, 0, stream>>>(sb, wtQ, bqkv, nullptr, big, 3072, 1024);
  // ctx = attention(q,k,v)              [4096][1024] f16
  attn_kernel<<<dim3(32, 32), blk, 0, stream>>>(big, big + 1024, big + 2048, ctx, 3072);
  // t = s + ctx @ Wo + bo
  gemm_kernel<2><<<dim3(8, 32), blk, 0, stream>>>(ctx, wtO, bo, s32, t32, 1024, 1024);
  // y = LN(t)
  ln_kernel<<<4096, blk, 0, stream>>>(t32, g1, b1, y32, ybuf);
  // f1 = relu(y @ Wf1 + bf1)            [4096][4096] f16 in big
  gemm_kernel<1><<<dim3(32, 32), blk, 0, stream>>>(ybuf, wtF1, bf1, nullptr, big, 4096, 1024);
  // t = y + f1 @ Wf2 + bf2
  gemm_kernel<2><<<dim3(8, 32), blk, 0, stream>>>(big, wtF2, bf2, y32, t32, 1024, 4096);
  // out = LN(t)
  ln_kernel<<<4096, blk, 0, stream>>>(t32, g2, b2, (float*)d_out, nullptr);
}

// Round 3
// 378.454 us; speedup vs baseline: 1.1519x; 1.1519x over previous
//
#include <hip/hip_runtime.h>
#include <cstdint>
#include <cstddef>

typedef _Float16 f16;
typedef _Float16 f16x8 __attribute__((ext_vector_type(8)));
typedef _Float16 f16x4 __attribute__((ext_vector_type(4)));
typedef float    f32x4 __attribute__((ext_vector_type(4)));
typedef float    f32x16 __attribute__((ext_vector_type(16)));

#define MFMA16(a,b,c) __builtin_amdgcn_mfma_f32_16x16x32_f16(a, b, c, 0, 0, 0)
#define MFMA32(a,b,c) __builtin_amdgcn_mfma_f32_32x32x16_f16(a, b, c, 0, 0, 0)

static __device__ __forceinline__ void gload_lds16(const void* g, void* l) {
  __builtin_amdgcn_global_load_lds(
      (const __attribute__((address_space(1))) unsigned int*)g,
      (__attribute__((address_space(3))) unsigned int*)l, 16, 0, 0);
}

static __device__ __forceinline__ int pkh(float a, float b) {
  auto t = __builtin_amdgcn_cvt_pkrtz(a, b);   // __fp16 x2
  return __builtin_bit_cast(int, t);
}

// ---------------------------------------------------------------------------
// elementwise f32 -> f16 cast (vectorized)
__global__ __launch_bounds__(256) void cast_kernel(const float* __restrict__ x,
                                                   f16* __restrict__ y, int n4) {
  int i = blockIdx.x * 256 + threadIdx.x;
  if (i < n4) {
    float4 v = ((const float4*)x)[i];
    f16x4 h;
    h[0] = (f16)v.x; h[1] = (f16)v.y; h[2] = (f16)v.z; h[3] = (f16)v.w;
    *(f16x4*)(y + (size_t)i * 4) = h;
  }
}

// ---------------------------------------------------------------------------
// W [K][N] f32 row-major  ->  Wt [N][K] f16 row-major (optionally scaled)
__global__ __launch_bounds__(256) void wtrans(const float* __restrict__ W,
                                              f16* __restrict__ Wt, int K, int N,
                                              float scale) {
  __shared__ float tile[32][33];
  const int n0 = blockIdx.x * 32, k0 = blockIdx.y * 32;
  const int c = threadIdx.x & 31, r = threadIdx.x >> 5;  // r: 0..7
#pragma unroll
  for (int i = 0; i < 4; i++) {
    int row = r + i * 8;
    tile[row][c] = W[(size_t)(k0 + row) * N + n0 + c];
  }
  __syncthreads();
#pragma unroll
  for (int i = 0; i < 4; i++) {
    int row = r + i * 8;
    Wt[(size_t)(n0 + row) * K + k0 + c] = (f16)(tile[c][row] * scale);
  }
}

// fused qkv bias, with q pre-scaled by 1/sqrt(64)
__global__ __launch_bounds__(256) void qkvbias_kernel(const float* __restrict__ bq,
                                                      const float* __restrict__ bk,
                                                      const float* __restrict__ bv,
                                                      float* __restrict__ bqkv) {
  int i = blockIdx.x * 256 + threadIdx.x;
  if (i < 1024)       bqkv[i] = bq[i] * 0.125f;
  else if (i < 2048)  bqkv[i] = bk[i - 1024];
  else if (i < 3072)  bqkv[i] = bv[i - 2048];
}

// ---------------------------------------------------------------------------
// GEMM: out[M][N] = epilogue(A[M][K]_f16 @ W^T[N][K]_f16 + bias)
// MODE 0: f16 store   MODE 1: relu + f16 store   MODE 2: f32 store + residual
template <int MODE>
__global__ __launch_bounds__(256, 2)
void gemm_kernel(const f16* __restrict__ A, const f16* __restrict__ W,
                 const float* __restrict__ bias, const float* __restrict__ res,
                 void* __restrict__ out, int N, int K) {
  __shared__ __align__(16) f16 lsA[128 * 64];
  __shared__ __align__(16) f16 lsB[128 * 64];
  const int tid  = threadIdx.x;
  const int lane = tid & 63;
  const int wid  = tid >> 6;
  const int frow = lane & 15;
  const int kgrp = lane >> 4;
  const int wm = wid >> 1, wn = wid & 1;
  const int bn = blockIdx.x, bm = blockIdx.y;

  const f32x4 zero4 = {0.f, 0.f, 0.f, 0.f};
  f32x4 acc[4][4];
#pragma unroll
  for (int i = 0; i < 4; i++)
#pragma unroll
    for (int j = 0; j < 4; j++) acc[i][j] = zero4;

  const f16* aSrc[4]; const f16* bSrc[4]; int lOff[4];
#pragma unroll
  for (int i = 0; i < 4; i++) {
    int c_lin = i * 256 + wid * 64 + lane;       // chunk id (16B units)
    int row = c_lin >> 3;
    int ch  = (c_lin & 7) ^ (row & 7);           // inverse-swizzled source chunk
    aSrc[i] = A + (size_t)(bm * 128 + row) * K + ch * 8;
    bSrc[i] = W + (size_t)(bn * 128 + row) * K + ch * 8;
    lOff[i] = (i * 256 + wid * 64) * 8;          // wave-uniform LDS base (elems)
  }

  const int nk = K >> 6;
  for (int ks = 0; ks < nk; ++ks) {
#pragma unroll
    for (int i = 0; i < 4; i++) {
      gload_lds16(aSrc[i] + ks * 64, &lsA[lOff[i]]);
      gload_lds16(bSrc[i] + ks * 64, &lsB[lOff[i]]);
    }
    __syncthreads();
#pragma unroll
    for (int kk = 0; kk < 2; kk++) {
      f16x8 af[4], bf[4];
#pragma unroll
      for (int i = 0; i < 4; i++) {
        int row = wm * 64 + i * 16 + frow;
        af[i] = *(const f16x8*)&lsA[row * 64 + (((kk * 4 + kgrp) ^ (row & 7)) << 3)];
      }
#pragma unroll
      for (int j = 0; j < 4; j++) {
        int row = wn * 64 + j * 16 + frow;
        bf[j] = *(const f16x8*)&lsB[row * 64 + (((kk * 4 + kgrp) ^ (row & 7)) << 3)];
      }
#pragma unroll
      for (int i = 0; i < 4; i++)
#pragma unroll
        for (int j = 0; j < 4; j++) acc[i][j] = MFMA16(af[i], bf[j], acc[i][j]);
    }
    __syncthreads();
  }

#pragma unroll
  for (int j = 0; j < 4; j++) {
    const int col = bn * 128 + wn * 64 + j * 16 + frow;
    const float bb = bias[col];
#pragma unroll
    for (int i = 0; i < 4; i++) {
      const int row0 = bm * 128 + wm * 64 + i * 16 + kgrp * 4;
#pragma unroll
      for (int r = 0; r < 4; r++) {
        float v = acc[i][j][r] + bb;
        const size_t idx = (size_t)(row0 + r) * N + col;
        if (MODE == 1) v = fmaxf(v, 0.f);
        if (MODE == 2) ((float*)out)[idx] = v + res[idx];
        else           ((f16*)out)[idx]   = (f16)v;
      }
    }
  }
}

// ---------------------------------------------------------------------------
// Flash attention, swapped-QK^T 32x32 structure.
// Q/K/V: [B*S][ldq] f16, head h = cols h*64..h*64+63. Q pre-scaled by 1/8.
// Block: 4 waves x 32 q-rows = 128 q rows; KV tiles of 64 (2 sub-tiles of 32).
// Per lane: one q column (q = lane&31); S^T via mfma(K,Q); softmax lane-local;
// P packed in-register (cvt_pkrtz + half-swap); O^T += mfma(V^T, P^T).
__global__ __launch_bounds__(256, 2)
void attn_kernel(const f16* __restrict__ Qp, const f16* __restrict__ Kp,
                 const f16* __restrict__ Vp, f16* __restrict__ Op, int ldq) {
  __shared__ __align__(16) f16 lsK[64 * 64];   // swizzled rows (16B-chunk XOR)
  __shared__ __align__(16) f16 lsVt[64 * 72];  // V^T, stride 72
  const int tid = threadIdx.x, lane = tid & 63, wid = tid >> 6;
  const int qcol = lane & 31;
  const int hi = lane >> 5;
  const int qt = blockIdx.x;
  const int b = blockIdx.y >> 4, h = blockIdx.y & 15;
  const size_t rb = (size_t)b * 2048;
  const int hc = h * 64;
  const int qrow = qt * 128 + wid * 32 + qcol;

  // Q fragment (B operand): lane holds Q[qrow][kc*16 + hi*8 + e]
  f16x8 qf[4];
  {
    const f16* qp = Qp + (rb + qrow) * ldq + hc;
#pragma unroll
    for (int kc = 0; kc < 4; kc++) qf[kc] = *(const f16x8*)(qp + kc * 16 + hi * 8);
  }

  f32x16 ot0, ot1;
#pragma unroll
  for (int i = 0; i < 16; i++) { ot0[i] = 0.f; ot1[i] = 0.f; }
  float mrun = -1e30f, lrun = 0.f;

  // K staging sources (chunk-XOR swizzled), wave-uniform LDS bases
  const f16* kSrc[2]; int kOff[2];
#pragma unroll
  for (int i = 0; i < 2; i++) {
    int c = i * 256 + wid * 64 + lane;
    int row = c >> 3, ch = (c & 7) ^ (row & 7);
    kSrc[i] = Kp + (rb + row) * ldq + hc + ch * 8;
    kOff[i] = (i * 256 + wid * 64) * 8;
  }
  const f16* vSrc = Vp + (rb + lane) * ldq + hc + wid * 16;

  for (int kt = 0; kt < 32; ++kt) {
    // ---- stage K (global_load_lds, swizzled) + V^T (reg transpose) ----
    gload_lds16(kSrc[0] + (size_t)kt * 64 * ldq, &lsK[kOff[0]]);
    gload_lds16(kSrc[1] + (size_t)kt * 64 * ldq, &lsK[kOff[1]]);
    {
      const f16* vp = vSrc + (size_t)kt * 64 * ldq;
      f16x8 v0 = *(const f16x8*)vp;
      f16x8 v1 = *(const f16x8*)(vp + 8);
#pragma unroll
      for (int jj = 0; jj < 8; jj++) lsVt[(wid * 16 + jj) * 72 + lane] = v0[jj];
#pragma unroll
      for (int jj = 0; jj < 8; jj++) lsVt[(wid * 16 + 8 + jj) * 72 + lane] = v1[jj];
    }
    __syncthreads();

#pragma unroll
    for (int st = 0; st < 2; ++st) {
      // ---- S^T[kv32][q32] = K_tile @ Q^T  (K=64 via 4 chunks) ----
      f32x16 sa;
#pragma unroll
      for (int i = 0; i < 16; i++) sa[i] = 0.f;
#pragma unroll
      for (int kc = 0; kc < 4; kc++) {
        const int krow = st * 32 + qcol;   // A row = kv (lane&31)
        f16x8 ak = *(const f16x8*)&lsK[krow * 64 + (((kc * 2 + hi) ^ (lane & 7)) << 3)];
        sa = MFMA32(ak, qf[kc], sa);
      }

      // ---- online softmax (one q per lane; kv lane-local + half-swap) ----
      float pr[16];
#pragma unroll
      for (int r = 0; r < 16; r++) pr[r] = sa[r];
      float pmax = pr[0];
#pragma unroll
      for (int r = 1; r < 16; r++) pmax = fmaxf(pmax, pr[r]);
      pmax = fmaxf(pmax, __shfl_xor(pmax, 32));
      if (__any(pmax > mrun + 8.f)) {      // defer-max (T13)
        float mn = fmaxf(mrun, pmax);
        float fac = __expf(mrun - mn);
        mrun = mn;
        lrun *= fac;
#pragma unroll
        for (int i = 0; i < 16; i++) { ot0[i] *= fac; ot1[i] *= fac; }
      }
      float ps = 0.f;
#pragma unroll
      for (int r = 0; r < 16; r++) { pr[r] = __expf(pr[r] - mrun); ps += pr[r]; }
      ps += __shfl_xor(ps, 32);
      lrun += ps;

      // ---- pack P^T fragments + PV:  O^T += V^T @ P^T ----
#pragma unroll
      for (int c0 = 0; c0 < 2; c0++) {
        const int c8 = c0 * 8;
        int a0 = pkh(pr[c8 + 0], pr[c8 + 1]);
        int a1 = pkh(pr[c8 + 2], pr[c8 + 3]);
        int b0 = pkh(pr[c8 + 4], pr[c8 + 5]);
        int b1 = pkh(pr[c8 + 6], pr[c8 + 7]);
        int sa0 = __shfl_xor(a0, 32), sb0 = __shfl_xor(b0, 32);
        int sa1 = __shfl_xor(a1, 32), sb1 = __shfl_xor(b1, 32);
        int4 wv;
        wv.x = hi ? sb0 : a0;
        wv.y = hi ? sb1 : a1;
        wv.z = hi ? b0 : sa0;
        wv.w = hi ? b1 : sa1;
        f16x8 pb = __builtin_bit_cast(f16x8, wv);
        const int kvo = st * 32 + c0 * 16 + hi * 8;
        {
          f16x8 av = *(const f16x8*)&lsVt[(qcol) * 72 + kvo];
          ot0 = MFMA32(av, pb, ot0);
        }
        {
          f16x8 av = *(const f16x8*)&lsVt[(32 + qcol) * 72 + kvo];
          ot1 = MFMA32(av, pb, ot1);
        }
      }
    }
    __syncthreads();
  }

  // ---- epilogue: O = O^T / l ----
  const float rinv = 1.f / lrun;
  f16* op = Op + (rb + qrow) * 1024 + hc;
#pragma unroll
  for (int rr = 0; rr < 16; rr += 2) {
    const int d = (rr & 3) + 8 * (rr >> 2) + 4 * hi;
    *(int*)(op + d)      = pkh(ot0[rr] * rinv, ot0[rr + 1] * rinv);
    *(int*)(op + 32 + d) = pkh(ot1[rr] * rinv, ot1[rr + 1] * rinv);
  }
}

// ---------------------------------------------------------------------------
// LayerNorm over D=1024 per row; writes f32 (of) and optional f16 (ob).
__global__ __launch_bounds__(256)
void ln_kernel(const float* __restrict__ x, const float* __restrict__ g,
               const float* __restrict__ be, float* __restrict__ of,
               f16* __restrict__ ob) {
  const int row = blockIdx.x, t = threadIdx.x;
  const float4 v = ((const float4*)(x + (size_t)row * 1024))[t];
  float s = v.x + v.y + v.z + v.w;
  float q = v.x * v.x + v.y * v.y + v.z * v.z + v.w * v.w;
#pragma unroll
  for (int off = 1; off < 64; off <<= 1) {
    s += __shfl_xor(s, off);
    q += __shfl_xor(q, off);
  }
  __shared__ float ss[4], sq[4];
  if ((t & 63) == 0) { ss[t >> 6] = s; sq[t >> 6] = q; }
  __syncthreads();
  s = ss[0] + ss[1] + ss[2] + ss[3];
  q = sq[0] + sq[1] + sq[2] + sq[3];
  const float mean = s * (1.f / 1024.f);
  const float var  = q * (1.f / 1024.f) - mean * mean;
  const float rstd = rsqrtf(var + 1e-5f);
  const float4 gv = ((const float4*)g)[t];
  const float4 bv = ((const float4*)be)[t];
  float4 ov;
  ov.x = (v.x - mean) * rstd * gv.x + bv.x;
  ov.y = (v.y - mean) * rstd * gv.y + bv.y;
  ov.z = (v.z - mean) * rstd * gv.z + bv.z;
  ov.w = (v.w - mean) * rstd * gv.w + bv.w;
  if (of) ((float4*)(of + (size_t)row * 1024))[t] = ov;
  if (ob) {
    f16x4 hv;
    hv[0] = (f16)ov.x; hv[1] = (f16)ov.y; hv[2] = (f16)ov.z; hv[3] = (f16)ov.w;
    *(f16x4*)(ob + (size_t)row * 1024 + t * 4) = hv;
  }
}

// ---------------------------------------------------------------------------
extern "C" void kernel_launch(void* const* d_in, const int* in_sizes, int n_in,
                              void* d_out, int out_size, void* d_ws, size_t ws_size,
                              hipStream_t stream) {
  const float* x   = (const float*)d_in[0];
  const float* pW1 = (const float*)d_in[1];
  const float* pb1 = (const float*)d_in[2];
  const float* pW2 = (const float*)d_in[3];
  const float* pb2 = (const float*)d_in[4];
  const float* gp  = (const float*)d_in[5];
  const float* bp  = (const float*)d_in[6];
  const float* Wq  = (const float*)d_in[7];
  const float* bq  = (const float*)d_in[8];
  const float* Wk  = (const float*)d_in[9];
  const float* bk  = (const float*)d_in[10];
  const float* Wv  = (const float*)d_in[11];
  const float* bv  = (const float*)d_in[12];
  const float* Wo  = (const float*)d_in[13];
  const float* bo  = (const float*)d_in[14];
  const float* g1  = (const float*)d_in[15];
  const float* b1  = (const float*)d_in[16];
  const float* Wf1 = (const float*)d_in[17];
  const float* bf1 = (const float*)d_in[18];
  const float* Wf2 = (const float*)d_in[19];
  const float* bf2 = (const float*)d_in[20];
  const float* g2  = (const float*)d_in[21];
  const float* b2  = (const float*)d_in[22];

  char* ws = (char*)d_ws;
  const size_t MB = 1024 * 1024;
  if (ws_size < 121 * MB) return;  // need ~120.1 MB scratch

  f16*   wtP1 = (f16*)(ws);             // [2048][1024]  4 MB
  f16*   wtP2 = (f16*)(ws + 4 * MB);    // [1024][2048]  4 MB
  f16*   wtQ  = (f16*)(ws + 8 * MB);    // [1024][1024]  2 MB (Q,K,V contiguous -> fused [3072][1024])
  f16*   wtK  = (f16*)(ws + 10 * MB);
  f16*   wtV  = (f16*)(ws + 12 * MB);
  f16*   wtO  = (f16*)(ws + 14 * MB);
  f16*   wtF1 = (f16*)(ws + 16 * MB);   // [4096][1024]  8 MB
  f16*   wtF2 = (f16*)(ws + 24 * MB);   // [1024][4096]  8 MB
  f16*   big  = (f16*)(ws + 32 * MB);   // 32 MB: h1 / fused qkv / f1
  float* t32  = (float*)(ws + 64 * MB); // 16 MB pre-LN tensor (first 8 MB also = xb)
  float* s32  = (float*)(ws + 80 * MB); // 16 MB
  float* y32  = (float*)(ws + 96 * MB); // 16 MB (first 8 MB also = sb)
  f16*   ybuf = (f16*)(ws + 112 * MB);  // 8 MB (also = ctx)
  float* bqkv = (float*)(ws + 120 * MB);// 12 KB fused qkv bias (q pre-scaled)
  f16* xb  = (f16*)t32;
  f16* sb  = (f16*)y32;
  f16* ctx = ybuf;

  dim3 blk(256);
  qkvbias_kernel<<<12, blk, 0, stream>>>(bq, bk, bv, bqkv);
  cast_kernel<<<4096, blk, 0, stream>>>(x, xb, 1048576);
  wtrans<<<dim3(64, 32),  blk, 0, stream>>>(pW1, wtP1, 1024, 2048, 1.f);
  wtrans<<<dim3(32, 64),  blk, 0, stream>>>(pW2, wtP2, 2048, 1024, 1.f);
  wtrans<<<dim3(32, 32),  blk, 0, stream>>>(Wq,  wtQ,  1024, 1024, 0.125f);
  wtrans<<<dim3(32, 32),  blk, 0, stream>>>(Wk,  wtK,  1024, 1024, 1.f);
  wtrans<<<dim3(32, 32),  blk, 0, stream>>>(Wv,  wtV,  1024, 1024, 1.f);
  wtrans<<<dim3(32, 32),  blk, 0, stream>>>(Wo,  wtO,  1024, 1024, 1.f);
  wtrans<<<dim3(128, 32), blk, 0, stream>>>(Wf1, wtF1, 1024, 4096, 1.f);
  wtrans<<<dim3(32, 128), blk, 0, stream>>>(Wf2, wtF2, 4096, 1024, 1.f);

  // h1 = relu(x @ pW1 + pb1)            [4096][2048] f16 in big
  gemm_kernel<1><<<dim3(16, 32), blk, 0, stream>>>(xb, wtP1, pb1, nullptr, big, 2048, 1024);
  // t = x + h1 @ pW2 + pb2              [4096][1024] f32
  gemm_kernel<2><<<dim3(8, 32), blk, 0, stream>>>(big, wtP2, pb2, x, t32, 1024, 2048);
  // s = LN(t)
  ln_kernel<<<4096, blk, 0, stream>>>(t32, gp, bp, s32, sb);
  // fused qkv = s @ [Wq|Wk|Wv] + [bq/8|bk|bv]   [4096][3072] f16 in big
  gemm_kernel<0><<<dim3(24, 32), blk, 0, stream>>>(sb, wtQ, bqkv, nullptr, big, 3072, 1024);
  // ctx = attention(q,k,v)              [4096][1024] f16
  attn_kernel<<<dim3(16, 32), blk, 0, stream>>>(big, big + 1024, big + 2048, ctx, 3072);
  // t = s + ctx @ Wo + bo
  gemm_kernel<2><<<dim3(8, 32), blk, 0, stream>>>(ctx, wtO, bo, s32, t32, 1024, 1024);
  // y = LN(t)
  ln_kernel<<<4096, blk, 0, stream>>>(t32, g1, b1, y32, ybuf);
  // f1 = relu(y @ Wf1 + bf1)            [4096][4096] f16 in big
  gemm_kernel<1><<<dim3(32, 32), blk, 0, stream>>>(ybuf, wtF1, bf1, nullptr, big, 4096, 1024);
  // t = y + f1 @ Wf2 + bf2
  gemm_kernel<2><<<dim3(8, 32), blk, 0, stream>>>(big, wtF2, bf2, y32, t32, 1024, 4096);
  // out = LN(t)
  ln_kernel<<<4096, blk, 0, stream>>>(t32, g2, b2, (float*)d_out, nullptr);
}

// Round 4
// 321.196 us; speedup vs baseline: 1.3572x; 1.1783x over previous
//
#include <hip/hip_runtime.h>
#include <cstdint>
#include <cstddef>

typedef _Float16 f16;
typedef _Float16 f16x8 __attribute__((ext_vector_type(8)));
typedef _Float16 f16x4 __attribute__((ext_vector_type(4)));
typedef float    f32x4 __attribute__((ext_vector_type(4)));
typedef float    f32x16 __attribute__((ext_vector_type(16)));

#define MFMA16(a,b,c) __builtin_amdgcn_mfma_f32_16x16x32_f16(a, b, c, 0, 0, 0)
#define MFMA32(a,b,c) __builtin_amdgcn_mfma_f32_32x32x16_f16(a, b, c, 0, 0, 0)

static __device__ __forceinline__ void gload_lds16(const void* g, void* l) {
  __builtin_amdgcn_global_load_lds(
      (const __attribute__((address_space(1))) unsigned int*)g,
      (__attribute__((address_space(3))) unsigned int*)l, 16, 0, 0);
}

static __device__ __forceinline__ int pkh(float a, float b) {
  auto t = __builtin_amdgcn_cvt_pkrtz(a, b);   // __fp16 x2
  return __builtin_bit_cast(int, t);
}

static __device__ __forceinline__ float ex2(float x) {
  return __builtin_amdgcn_exp2f(x);
}

// ---------------------------------------------------------------------------
// elementwise f32 -> f16 cast (vectorized)
__global__ __launch_bounds__(256) void cast_kernel(const float* __restrict__ x,
                                                   f16* __restrict__ y, int n4) {
  int i = blockIdx.x * 256 + threadIdx.x;
  if (i < n4) {
    float4 v = ((const float4*)x)[i];
    f16x4 h;
    h[0] = (f16)v.x; h[1] = (f16)v.y; h[2] = (f16)v.z; h[3] = (f16)v.w;
    *(f16x4*)(y + (size_t)i * 4) = h;
  }
}

// ---------------------------------------------------------------------------
// W [K][N] f32 row-major  ->  Wt [N][K] f16 row-major (optionally scaled)
__global__ __launch_bounds__(256) void wtrans(const float* __restrict__ W,
                                              f16* __restrict__ Wt, int K, int N,
                                              float scale) {
  __shared__ float tile[32][33];
  const int n0 = blockIdx.x * 32, k0 = blockIdx.y * 32;
  const int c = threadIdx.x & 31, r = threadIdx.x >> 5;  // r: 0..7
#pragma unroll
  for (int i = 0; i < 4; i++) {
    int row = r + i * 8;
    tile[row][c] = W[(size_t)(k0 + row) * N + n0 + c];
  }
  __syncthreads();
#pragma unroll
  for (int i = 0; i < 4; i++) {
    int row = r + i * 8;
    Wt[(size_t)(n0 + row) * K + k0 + c] = (f16)(tile[c][row] * scale);
  }
}

// fused qkv bias; q pre-scaled by 0.125*log2(e) (exp2-domain softmax)
__global__ __launch_bounds__(256) void qkvbias_kernel(const float* __restrict__ bq,
                                                      const float* __restrict__ bk,
                                                      const float* __restrict__ bv,
                                                      float* __restrict__ bqkv) {
  int i = blockIdx.x * 256 + threadIdx.x;
  if (i < 1024)       bqkv[i] = bq[i] * 0.18033688f;
  else if (i < 2048)  bqkv[i] = bk[i - 1024];
  else if (i < 3072)  bqkv[i] = bv[i - 2048];
}

// ---------------------------------------------------------------------------
// GEMM: out[M][BN-grid] = epilogue(A[M][K]_f16 @ W^T[N][K]_f16 + bias)
// MODE 0: f16 store   MODE 1: relu + f16 store   MODE 2: f32 store + residual
// MODE 3: f16 store, except cols>=2048 stored transposed to vt[bh][64][2048]
// BM=128, BN template (128: 4 waves 2x2; 64: 4 waves 4x1).
template <int MODE, int BN>
__global__ __launch_bounds__(256, 2)
void gemm_kernel(const f16* __restrict__ A, const f16* __restrict__ W,
                 const float* __restrict__ bias, const float* __restrict__ res,
                 void* __restrict__ out, f16* __restrict__ vt, int N, int K) {
  __shared__ __align__(16) f16 lsA[128 * 64];
  __shared__ __align__(16) f16 lsB[BN * 64];
  constexpr int MI = (BN == 128) ? 4 : 2;   // 16-row tiles per wave (M)
  constexpr int NB = (BN == 128) ? 4 : 2;   // B staging chunks per thread
  const int tid  = threadIdx.x;
  const int lane = tid & 63;
  const int wid  = tid >> 6;
  const int frow = lane & 15;
  const int kgrp = lane >> 4;
  const int wmBase = (BN == 128) ? (wid >> 1) * 64 : wid * 32;
  const int wnBase = (BN == 128) ? (wid & 1) * 64 : 0;
  const int bn = blockIdx.x, bm = blockIdx.y;

  const f32x4 zero4 = {0.f, 0.f, 0.f, 0.f};
  f32x4 acc[MI][4];
#pragma unroll
  for (int i = 0; i < MI; i++)
#pragma unroll
    for (int j = 0; j < 4; j++) acc[i][j] = zero4;

  const f16* aSrc[4]; int lOffA[4];
  const f16* bSrc[NB]; int lOffB[NB];
#pragma unroll
  for (int i = 0; i < 4; i++) {
    int c_lin = i * 256 + wid * 64 + lane;       // chunk id (16B units)
    int row = c_lin >> 3;
    int ch  = (c_lin & 7) ^ (row & 7);           // inverse-swizzled source chunk
    aSrc[i] = A + (size_t)(bm * 128 + row) * K + ch * 8;
    lOffA[i] = (i * 256 + wid * 64) * 8;
  }
#pragma unroll
  for (int i = 0; i < NB; i++) {
    int c_lin = i * 256 + wid * 64 + lane;
    int row = c_lin >> 3;
    int ch  = (c_lin & 7) ^ (row & 7);
    bSrc[i] = W + (size_t)(bn * BN + row) * K + ch * 8;
    lOffB[i] = (i * 256 + wid * 64) * 8;
  }

  const int nk = K >> 6;
  for (int ks = 0; ks < nk; ++ks) {
#pragma unroll
    for (int i = 0; i < 4; i++) gload_lds16(aSrc[i] + ks * 64, &lsA[lOffA[i]]);
#pragma unroll
    for (int i = 0; i < NB; i++) gload_lds16(bSrc[i] + ks * 64, &lsB[lOffB[i]]);
    __syncthreads();
#pragma unroll
    for (int kk = 0; kk < 2; kk++) {
      f16x8 af[MI], bf[4];
#pragma unroll
      for (int i = 0; i < MI; i++) {
        int row = wmBase + i * 16 + frow;
        af[i] = *(const f16x8*)&lsA[row * 64 + (((kk * 4 + kgrp) ^ (row & 7)) << 3)];
      }
#pragma unroll
      for (int j = 0; j < 4; j++) {
        int row = wnBase + j * 16 + frow;
        bf[j] = *(const f16x8*)&lsB[row * 64 + (((kk * 4 + kgrp) ^ (row & 7)) << 3)];
      }
#pragma unroll
      for (int i = 0; i < MI; i++)
#pragma unroll
        for (int j = 0; j < 4; j++) acc[i][j] = MFMA16(af[i], bf[j], acc[i][j]);
    }
    __syncthreads();
  }

#pragma unroll
  for (int j = 0; j < 4; j++) {
    const int col = bn * BN + wnBase + j * 16 + frow;
    const float bb = bias[col];
#pragma unroll
    for (int i = 0; i < MI; i++) {
      const int row0 = bm * 128 + wmBase + i * 16 + kgrp * 4;
      if (MODE == 3 && col >= 2048) {
        // V region: store transposed, packed 4 tokens (= 4 kv) per 8B
        const int vcol = col - 2048;
        const int bh = (row0 >> 11) * 16 + (vcol >> 6);
        const int d  = vcol & 63;
        const int kv = row0 & 2047;
        f16x4 pk;
#pragma unroll
        for (int r = 0; r < 4; r++) pk[r] = (f16)(acc[i][j][r] + bb);
        *(f16x4*)(vt + ((size_t)bh * 64 + d) * 2048 + kv) = pk;
      } else {
#pragma unroll
        for (int r = 0; r < 4; r++) {
          float v = acc[i][j][r] + bb;
          const size_t idx = (size_t)(row0 + r) * N + col;
          if (MODE == 1) v = fmaxf(v, 0.f);
          if (MODE == 2) ((float*)out)[idx] = v + res[idx];
          else           ((f16*)out)[idx]   = (f16)v;
        }
      }
    }
  }
}

// ---------------------------------------------------------------------------
// Flash attention, swapped-QK^T 32x32 structure, 2-phase prefetch.
// Q/K: [B*S][ldq] f16 (head h at cols h*64..); V^T: [bh][64 d][2048 kv] f16.
// Q pre-scaled by 0.125*log2(e); softmax in exp2 domain.
// Block: 4 waves x 32 q = 128 q rows. KV tiles of 64, double-buffered LDS,
// staged entirely via global_load_lds (chunk-XOR swizzle both sides).
__global__ __launch_bounds__(256, 2)
void attn_kernel(const f16* __restrict__ Qp, const f16* __restrict__ Kp,
                 const f16* __restrict__ Vt, f16* __restrict__ Op, int ldq) {
  __shared__ __align__(16) f16 lsKb[2 * 64 * 64];
  __shared__ __align__(16) f16 lsVb[2 * 64 * 64];
  const int tid = threadIdx.x, lane = tid & 63, wid = tid >> 6;
  const int qcol = lane & 31;
  const int hi = lane >> 5;
  // XCD-bijective swizzle: each XCD gets 4 (b,h) pairs (K/V L2-resident)
  const int bid = blockIdx.x;
  const int bh = ((bid & 7) << 2) | ((bid >> 3) & 3);
  const int qt = bid >> 5;
  const int b = bh >> 4, h = bh & 15;
  const size_t rb = (size_t)b * 2048;
  const int hc = h * 64;
  const int qrow = qt * 128 + wid * 32 + qcol;

  // Q fragment (B operand): lane holds Q[qrow][kc*16 + hi*8 + e]
  f16x8 qf[4];
  {
    const f16* qp = Qp + (rb + qrow) * ldq + hc;
#pragma unroll
    for (int kc = 0; kc < 4; kc++) qf[kc] = *(const f16x8*)(qp + kc * 16 + hi * 8);
  }

  f32x16 ot0, ot1;
#pragma unroll
  for (int i = 0; i < 16; i++) { ot0[i] = 0.f; ot1[i] = 0.f; }
  float mrun = -1e30f, lrun = 0.f;

  // staging sources (chunk-XOR pre-swizzled global addresses)
  const f16 *kS0, *kS1, *vS0, *vS1;
  int off0, off1;
  {
    int c0 = wid * 64 + lane;
    int r0 = c0 >> 3, ch0 = (c0 & 7) ^ (r0 & 7);
    int c1 = 256 + wid * 64 + lane;
    int r1 = c1 >> 3, ch1 = (c1 & 7) ^ (r1 & 7);
    kS0 = Kp + (rb + r0) * ldq + hc + ch0 * 8;
    kS1 = Kp + (rb + r1) * ldq + hc + ch1 * 8;
    const f16* vbase = Vt + (size_t)bh * 64 * 2048;
    vS0 = vbase + (size_t)r0 * 2048 + ch0 * 8;
    vS1 = vbase + (size_t)r1 * 2048 + ch1 * 8;
    off0 = (wid * 64) * 8;
    off1 = (256 + wid * 64) * 8;
  }

#define STAGE(T, PB)                                                     \
  {                                                                      \
    f16* kd = lsKb + (PB) * 4096;                                        \
    f16* vd = lsVb + (PB) * 4096;                                        \
    const size_t ko = (size_t)(T) * 64 * ldq;                            \
    const size_t vo = (size_t)(T) * 64;                                  \
    gload_lds16(kS0 + ko, kd + off0);                                    \
    gload_lds16(kS1 + ko, kd + off1);                                    \
    gload_lds16(vS0 + vo, vd + off0);                                    \
    gload_lds16(vS1 + vo, vd + off1);                                    \
  }

  STAGE(0, 0);
  asm volatile("s_waitcnt vmcnt(0)" ::: "memory");
  __builtin_amdgcn_s_barrier();

  for (int kt = 0; kt < 32; ++kt) {
    const int cur = kt & 1;
    if (kt < 31) STAGE(kt + 1, cur ^ 1);   // prefetch overlaps compute below
    const f16* kb = lsKb + cur * 4096;
    const f16* vb = lsVb + cur * 4096;

#pragma unroll
    for (int st = 0; st < 2; ++st) {
      // ---- S^T[kv32][q32] = K_tile @ Q^T ----
      f32x16 sa;
#pragma unroll
      for (int i = 0; i < 16; i++) sa[i] = 0.f;
      const int krow = st * 32 + qcol;
#pragma unroll
      for (int kc = 0; kc < 4; kc++) {
        f16x8 ak = *(const f16x8*)&kb[krow * 64 + (((kc * 2 + hi) ^ (krow & 7)) << 3)];
        sa = MFMA32(ak, qf[kc], sa);
      }

      // ---- online softmax (exp2 domain, one q per lane) ----
      float pr[16];
#pragma unroll
      for (int r = 0; r < 16; r++) pr[r] = sa[r];
      float pmax = pr[0];
#pragma unroll
      for (int r = 1; r < 16; r++) pmax = fmaxf(pmax, pr[r]);
      pmax = fmaxf(pmax, __shfl_xor(pmax, 32));
      if (__any(pmax > mrun + 11.54f)) {   // defer-max (T13), 8/ln2
        float mn = fmaxf(mrun, pmax);
        float fac = ex2(mrun - mn);
        mrun = mn;
        lrun *= fac;
#pragma unroll
        for (int i = 0; i < 16; i++) { ot0[i] *= fac; ot1[i] *= fac; }
      }
      float ps = 0.f;
#pragma unroll
      for (int r = 0; r < 16; r++) { pr[r] = ex2(pr[r] - mrun); ps += pr[r]; }
      ps += __shfl_xor(ps, 32);
      lrun += ps;

      // ---- pack P^T fragments + PV:  O^T += V^T @ P^T ----
#pragma unroll
      for (int c0 = 0; c0 < 2; c0++) {
        const int c8 = c0 * 8;
        int a0 = pkh(pr[c8 + 0], pr[c8 + 1]);
        int a1 = pkh(pr[c8 + 2], pr[c8 + 3]);
        int b0 = pkh(pr[c8 + 4], pr[c8 + 5]);
        int b1 = pkh(pr[c8 + 6], pr[c8 + 7]);
        int sa0 = __shfl_xor(a0, 32), sb0 = __shfl_xor(b0, 32);
        int sa1 = __shfl_xor(a1, 32), sb1 = __shfl_xor(b1, 32);
        int4 wv;
        wv.x = hi ? sb0 : a0;
        wv.y = hi ? sb1 : a1;
        wv.z = hi ? b0 : sa0;
        wv.w = hi ? b1 : sa1;
        f16x8 pfrag = __builtin_bit_cast(f16x8, wv);
        const int ch = st * 4 + c0 * 2 + hi;   // 16B chunk of kv window
        {
          const int vr = qcol;
          f16x8 av = *(const f16x8*)&vb[vr * 64 + ((ch ^ (vr & 7)) << 3)];
          ot0 = MFMA32(av, pfrag, ot0);
        }
        {
          const int vr = 32 + qcol;
          f16x8 av = *(const f16x8*)&vb[vr * 64 + ((ch ^ (vr & 7)) << 3)];
          ot1 = MFMA32(av, pfrag, ot1);
        }
      }
    }
    asm volatile("s_waitcnt vmcnt(0)" ::: "memory");  // prefetch landed
    __builtin_amdgcn_s_barrier();                     // all waves done w/ cur
  }
#undef STAGE

  // ---- epilogue: O = O^T / l ----
  const float rinv = 1.f / lrun;
  f16* op = Op + (rb + qrow) * 1024 + hc;
#pragma unroll
  for (int rr = 0; rr < 16; rr += 2) {
    const int d = (rr & 3) + 8 * (rr >> 2) + 4 * hi;
    *(int*)(op + d)      = pkh(ot0[rr] * rinv, ot0[rr + 1] * rinv);
    *(int*)(op + 32 + d) = pkh(ot1[rr] * rinv, ot1[rr + 1] * rinv);
  }
}

// ---------------------------------------------------------------------------
// LayerNorm over D=1024 per row; writes f32 (of) and optional f16 (ob).
__global__ __launch_bounds__(256)
void ln_kernel(const float* __restrict__ x, const float* __restrict__ g,
               const float* __restrict__ be, float* __restrict__ of,
               f16* __restrict__ ob) {
  const int row = blockIdx.x, t = threadIdx.x;
  const float4 v = ((const float4*)(x + (size_t)row * 1024))[t];
  float s = v.x + v.y + v.z + v.w;
  float q = v.x * v.x + v.y * v.y + v.z * v.z + v.w * v.w;
#pragma unroll
  for (int off = 1; off < 64; off <<= 1) {
    s += __shfl_xor(s, off);
    q += __shfl_xor(q, off);
  }
  __shared__ float ss[4], sq[4];
  if ((t & 63) == 0) { ss[t >> 6] = s; sq[t >> 6] = q; }
  __syncthreads();
  s = ss[0] + ss[1] + ss[2] + ss[3];
  q = sq[0] + sq[1] + sq[2] + sq[3];
  const float mean = s * (1.f / 1024.f);
  const float var  = q * (1.f / 1024.f) - mean * mean;
  const float rstd = rsqrtf(var + 1e-5f);
  const float4 gv = ((const float4*)g)[t];
  const float4 bv = ((const float4*)be)[t];
  float4 ov;
  ov.x = (v.x - mean) * rstd * gv.x + bv.x;
  ov.y = (v.y - mean) * rstd * gv.y + bv.y;
  ov.z = (v.z - mean) * rstd * gv.z + bv.z;
  ov.w = (v.w - mean) * rstd * gv.w + bv.w;
  if (of) ((float4*)(of + (size_t)row * 1024))[t] = ov;
  if (ob) {
    f16x4 hv;
    hv[0] = (f16)ov.x; hv[1] = (f16)ov.y; hv[2] = (f16)ov.z; hv[3] = (f16)ov.w;
    *(f16x4*)(ob + (size_t)row * 1024 + t * 4) = hv;
  }
}

// ---------------------------------------------------------------------------
extern "C" void kernel_launch(void* const* d_in, const int* in_sizes, int n_in,
                              void* d_out, int out_size, void* d_ws, size_t ws_size,
                              hipStream_t stream) {
  const float* x   = (const float*)d_in[0];
  const float* pW1 = (const float*)d_in[1];
  const float* pb1 = (const float*)d_in[2];
  const float* pW2 = (const float*)d_in[3];
  const float* pb2 = (const float*)d_in[4];
  const float* gp  = (const float*)d_in[5];
  const float* bp  = (const float*)d_in[6];
  const float* Wq  = (const float*)d_in[7];
  const float* bq  = (const float*)d_in[8];
  const float* Wk  = (const float*)d_in[9];
  const float* bk  = (const float*)d_in[10];
  const float* Wv  = (const float*)d_in[11];
  const float* bv  = (const float*)d_in[12];
  const float* Wo  = (const float*)d_in[13];
  const float* bo  = (const float*)d_in[14];
  const float* g1  = (const float*)d_in[15];
  const float* b1  = (const float*)d_in[16];
  const float* Wf1 = (const float*)d_in[17];
  const float* bf1 = (const float*)d_in[18];
  const float* Wf2 = (const float*)d_in[19];
  const float* bf2 = (const float*)d_in[20];
  const float* g2  = (const float*)d_in[21];
  const float* b2  = (const float*)d_in[22];

  char* ws = (char*)d_ws;
  const size_t MB = 1024 * 1024;
  if (ws_size < 121 * MB) return;  // need ~120.1 MB scratch

  f16*   wtP1 = (f16*)(ws);             // [2048][1024]  4 MB
  f16*   wtP2 = (f16*)(ws + 4 * MB);    // [1024][2048]  4 MB
  f16*   wtQ  = (f16*)(ws + 8 * MB);    // [3072][1024]  6 MB fused qkv weights
  f16*   wtK  = (f16*)(ws + 10 * MB);
  f16*   wtV  = (f16*)(ws + 12 * MB);
  f16*   wtO  = (f16*)(ws + 14 * MB);   // [1024][1024]  2 MB
  f16*   wtF1 = (f16*)(ws + 16 * MB);   // [4096][1024]  8 MB
  f16*   wtF2 = (f16*)(ws + 24 * MB);   // [1024][4096]  8 MB
  f16*   big  = (f16*)(ws + 32 * MB);   // 32 MB: h1 / fused qk|v / f1
  float* t32  = (float*)(ws + 64 * MB); // 16 MB pre-LN tensor (first 8 MB also = xb)
  float* s32  = (float*)(ws + 80 * MB); // 16 MB
  float* y32  = (float*)(ws + 96 * MB); // 16 MB (first 8 MB also = sb)
  f16*   ybuf = (f16*)(ws + 112 * MB);  // 8 MB (also = ctx)
  float* bqkv = (float*)(ws + 120 * MB);// 12 KB fused qkv bias (q pre-scaled)
  f16* xb  = (f16*)t32;
  f16* sb  = (f16*)y32;
  f16* ctx = ybuf;
  f16* Vt  = big + (size_t)4096 * 3072; // V^T [32 bh][64 d][2048 kv], 8 MB tail of big

  dim3 blk(256);
  qkvbias_kernel<<<12, blk, 0, stream>>>(bq, bk, bv, bqkv);
  cast_kernel<<<4096, blk, 0, stream>>>(x, xb, 1048576);
  wtrans<<<dim3(64, 32),  blk, 0, stream>>>(pW1, wtP1, 1024, 2048, 1.f);
  wtrans<<<dim3(32, 64),  blk, 0, stream>>>(pW2, wtP2, 2048, 1024, 1.f);
  wtrans<<<dim3(32, 32),  blk, 0, stream>>>(Wq,  wtQ,  1024, 1024, 0.18033688f);
  wtrans<<<dim3(32, 32),  blk, 0, stream>>>(Wk,  wtK,  1024, 1024, 1.f);
  wtrans<<<dim3(32, 32),  blk, 0, stream>>>(Wv,  wtV,  1024, 1024, 1.f);
  wtrans<<<dim3(32, 32),  blk, 0, stream>>>(Wo,  wtO,  1024, 1024, 1.f);
  wtrans<<<dim3(128, 32), blk, 0, stream>>>(Wf1, wtF1, 1024, 4096, 1.f);
  wtrans<<<dim3(32, 128), blk, 0, stream>>>(Wf2, wtF2, 4096, 1024, 1.f);

  // h1 = relu(x @ pW1 + pb1)            [4096][2048] f16 in big
  gemm_kernel<1,128><<<dim3(16, 32), blk, 0, stream>>>(xb, wtP1, pb1, nullptr, big, nullptr, 2048, 1024);
  // t = x + h1 @ pW2 + pb2              [4096][1024] f32
  gemm_kernel<2,64><<<dim3(16, 32), blk, 0, stream>>>(big, wtP2, pb2, x, t32, nullptr, 1024, 2048);
  // s = LN(t)
  ln_kernel<<<4096, blk, 0, stream>>>(t32, gp, bp, s32, sb);
  // qkv = s @ [Wq|Wk|Wv] + bias; Q,K normal (ld 3072), V transposed into Vt
  gemm_kernel<3,128><<<dim3(24, 32), blk, 0, stream>>>(sb, wtQ, bqkv, nullptr, big, Vt, 3072, 1024);
  // ctx = attention(q,k,v)              [4096][1024] f16
  attn_kernel<<<512, blk, 0, stream>>>(big, big + 1024, Vt, ctx, 3072);
  // t = s + ctx @ Wo + bo
  gemm_kernel<2,64><<<dim3(16, 32), blk, 0, stream>>>(ctx, wtO, bo, s32, t32, nullptr, 1024, 1024);
  // y = LN(t)
  ln_kernel<<<4096, blk, 0, stream>>>(t32, g1, b1, y32, ybuf);
  // f1 = relu(y @ Wf1 + bf1)            [4096][4096] f16 in big
  gemm_kernel<1,128><<<dim3(32, 32), blk, 0, stream>>>(ybuf, wtF1, bf1, nullptr, big, nullptr, 4096, 1024);
  // t = y + f1 @ Wf2 + bf2
  gemm_kernel<2,64><<<dim3(16, 32), blk, 0, stream>>>(big, wtF2, bf2, y32, t32, nullptr, 1024, 4096);
  // out = LN(t)
  ln_kernel<<<4096, blk, 0, stream>>>(t32, g2, b2, (float*)d_out, nullptr);
}